// Round 8
// baseline (559.634 us; speedup 1.0000x reference)
//
#include <hip/hip_runtime.h>
#include <hip/hip_bf16.h>
#include <math.h>

#define B_    2
#define L_    1024
#define H_    12
#define D_    64
#define HID_  768
#define TOPK_ 32
#define NEG_  (-100000000.0f)
#define KP_   2304   // tripled K for split-bf16 GEMM

typedef __attribute__((ext_vector_type(8))) short short8;
typedef __attribute__((ext_vector_type(4))) short short4v;
typedef __attribute__((ext_vector_type(4))) float f32x4;

__device__ __forceinline__ void gload16(const void* g, void* l) {
    __builtin_amdgcn_global_load_lds((const __attribute__((address_space(1))) void*)g,
                                     (__attribute__((address_space(3))) void*)l, 16, 0, 0);
}

// ---------------------------------------------------------------------------
// bias vector for the fused qkv GEMM: [q_bias | zeros | v_bias]
// ---------------------------------------------------------------------------
__global__ void prep_bias(const float* __restrict__ qb_,
                          const float* __restrict__ vb_,
                          float* __restrict__ biasq) {
    int n = blockIdx.x * 256 + threadIdx.x;
    if (n >= 3 * HID_) return;
    float v = 0.f;
    if (n < HID_) v = qb_[n];
    else if (n >= 2 * HID_) v = vb_[n - 2 * HID_];
    biasq[n] = v;
}

// ---------------------------------------------------------------------------
// split fp32 A [2048][srcStride] (first 768 cols) -> bf16 [2048][2304] = [hi|hi|lo]
// ---------------------------------------------------------------------------
__global__ __launch_bounds__(256) void split_a(const float* __restrict__ src, int srcStride,
                                               __hip_bfloat16* __restrict__ dst) {
    int idx = blockIdx.x * 256 + threadIdx.x;           // 0 .. 2048*192-1
    int r = idx / 192, c4 = (idx - r * 192) * 4;
    const float4 x = *(const float4*)(src + (size_t)r * srcStride + c4);
    float xs[4] = {x.x, x.y, x.z, x.w};
    short4v h4, l4;
#pragma unroll
    for (int j = 0; j < 4; ++j) {
        __hip_bfloat16 h = __float2bfloat16(xs[j]);
        __hip_bfloat16 l = __float2bfloat16(xs[j] - __bfloat162float(h));
        h4[j] = *(short*)&h;
        l4[j] = *(short*)&l;
    }
    short* d = (short*)(dst + (size_t)r * KP_ + c4);
    *(short4v*)(d)         = h4;
    *(short4v*)(d + 768)   = h4;
    *(short4v*)(d + 1536)  = l4;
}

// ---------------------------------------------------------------------------
// transpose + split weights: src [768][N] f32 -> dst [N][2304] bf16 = [hi|lo|hi]
// 32x32 tiles via LDS; 8B vectorized stores (4 consecutive k per thread).
// ---------------------------------------------------------------------------
__global__ __launch_bounds__(256) void split_w(const float* __restrict__ src, int N,
                                               __hip_bfloat16* __restrict__ dst) {
    __shared__ float tile[32][33];
    const int n0 = blockIdx.x * 32, k0 = blockIdx.y * 32;
    const int tx = threadIdx.x & 31, ty = threadIdx.x >> 5;
#pragma unroll
    for (int p = 0; p < 4; ++p) {
        int r = p * 8 + ty;
        tile[r][tx] = src[(size_t)(k0 + r) * N + n0 + tx];
    }
    __syncthreads();
    const int kg = threadIdx.x & 7;        // 4-k group
    const int nl = threadIdx.x >> 3;       // 0..31
    short4v h4, l4;
#pragma unroll
    for (int e = 0; e < 4; ++e) {
        float xv = tile[kg * 4 + e][nl];
        __hip_bfloat16 h = __float2bfloat16(xv);
        __hip_bfloat16 l = __float2bfloat16(xv - __bfloat162float(h));
        h4[e] = *(short*)&h;
        l4[e] = *(short*)&l;
    }
    short* d = (short*)(dst + (size_t)(n0 + nl) * KP_ + k0 + kg * 4);
    *(short4v*)(d)        = h4;
    *(short4v*)(d + 768)  = l4;
    *(short4v*)(d + 1536) = h4;
}

// ---------------------------------------------------------------------------
// split-bf16 MFMA GEMM: C[M][ldc] = A'[M][2304] x Bt'[N][2304] + bias
// 256 threads (4 waves, 2x2); wave tile (BM/2 x BN/2); K-tile 64;
// LDS XOR-swizzled both sides; global_load_lds width-16 staging.
// ---------------------------------------------------------------------------
template<int BM, int BN>
__global__ __launch_bounds__(256) void gemm_split(
    const __hip_bfloat16* __restrict__ A,
    const __hip_bfloat16* __restrict__ Bt,
    const float* __restrict__ bias,
    float* __restrict__ C, int ldc)
{
    constexpr int NT  = KP_ / 64;       // 36 K-tiles
    constexpr int ACH = BM / 32;        // 4KB staging chunks for A
    constexpr int BCH = BN / 32;
    constexpr int MI  = BM / 32;        // 16x16 frags per wave
    constexpr int NI  = BN / 32;
    __shared__ __align__(16) char smem[(BM + BN) * 128];

    const int tid  = threadIdx.x;
    const int wid  = tid >> 6, lane = tid & 63;
    const int wr   = wid >> 1, wc = wid & 1;
    const int bm   = blockIdx.y * BM, bn = blockIdx.x * BN;
    const int r4   = lane >> 4, l15 = lane & 15;

    f32x4 acc[MI][NI];
#pragma unroll
    for (int mi = 0; mi < MI; ++mi)
#pragma unroll
        for (int ni = 0; ni < NI; ++ni) acc[mi][ni] = (f32x4){0.f, 0.f, 0.f, 0.f};

    const char* Ab  = (const char*)A;
    const char* Btb = (const char*)Bt;

    for (int kt = 0; kt < NT; ++kt) {
        __syncthreads();
#pragma unroll
        for (int c = 0; c < ACH; ++c) {
            int slot = c * 4096 + tid * 16;
            int R = slot >> 7, cb = (slot >> 4) & 7;
            const char* g = Ab + (size_t)(bm + R) * (KP_ * 2) + kt * 128 + ((cb ^ (R & 7)) << 4);
            gload16(g, smem + c * 4096 + wid * 1024);
        }
#pragma unroll
        for (int c = 0; c < BCH; ++c) {
            int slot = c * 4096 + tid * 16;
            int R = slot >> 7, cb = (slot >> 4) & 7;
            const char* g = Btb + (size_t)(bn + R) * (KP_ * 2) + kt * 128 + ((cb ^ (R & 7)) << 4);
            gload16(g, smem + BM * 128 + c * 4096 + wid * 1024);
        }
        __syncthreads();

#pragma unroll
        for (int kk = 0; kk < 2; ++kk) {
            short8 af[MI], bfv[NI];
#pragma unroll
            for (int mi = 0; mi < MI; ++mi) {
                int m_loc = wr * (BM / 2) + mi * 16 + l15;
                int off = (m_loc * 128 + kk * 64 + r4 * 16) ^ ((m_loc & 7) << 4);
                af[mi] = *(const short8*)(smem + off);
            }
#pragma unroll
            for (int ni = 0; ni < NI; ++ni) {
                int n_loc = wc * (BN / 2) + ni * 16 + l15;
                int off = BM * 128 + ((n_loc * 128 + kk * 64 + r4 * 16) ^ ((n_loc & 7) << 4));
                bfv[ni] = *(const short8*)(smem + off);
            }
#pragma unroll
            for (int mi = 0; mi < MI; ++mi)
#pragma unroll
                for (int ni = 0; ni < NI; ++ni)
                    acc[mi][ni] = __builtin_amdgcn_mfma_f32_16x16x32_bf16(
                        af[mi], bfv[ni], acc[mi][ni], 0, 0, 0);
        }
    }

#pragma unroll
    for (int mi = 0; mi < MI; ++mi) {
        int row = bm + wr * (BM / 2) + mi * 16 + r4 * 4;
#pragma unroll
        for (int ni = 0; ni < NI; ++ni) {
            int col = bn + wc * (BN / 2) + ni * 16 + l15;
            float bv = bias[col];
#pragma unroll
            for (int reg = 0; reg < 4; ++reg)
                C[(size_t)(row + reg) * ldc + col] = acc[mi][ni][reg] + bv;
        }
    }
}

// ---------------------------------------------------------------------------
// Sparse gather-attention. One block per (b,i); 384 threads.
// Thread (h=tid>>5, t=tid&31) owns one (t,h) score pair. No register V
// prefetch (round-5 spill lesson) — ctx uses bounded 8-wide load batches.
// ---------------------------------------------------------------------------
__global__ __launch_bounds__(384, 6) void attn_kernel(
    const float* __restrict__ qkv,   // [B*L][2304]  q|k|v (biases applied)
    const float* __restrict__ qb,    // [B*L][768]
    const float* __restrict__ rbe,   // [B*L][32][768]
    const int*   __restrict__ ridx,  // [B*L][32]
    const unsigned char* __restrict__ amask, // [B][L][L]
    const float* __restrict__ rel_pos,   // [B][12][L][L]
    const float* __restrict__ rel2d,     // [B][12][L][L]
    float* __restrict__ out)             // [B*L][768]
{
    const int bi = blockIdx.x;
    const int b = bi >> 10, i = bi & (L_ - 1);
    const int tid = threadIdx.x;
    const int h = tid >> 5, t = tid & 31;   // 384 = 12 heads x 32 slots
    const float scale = 0.125f;

    __shared__ __align__(16) float sQ[HID_];
    __shared__ __align__(16) float sQb[HID_];
    __shared__ int   sIdx[TOPK_];
    __shared__ unsigned char sFirst[TOPK_];
    __shared__ unsigned char sMask[TOPK_];
    __shared__ float sRel[H_][TOPK_];
    __shared__ float sBbox[H_][TOPK_];
    __shared__ float sScore[H_][TOPK_];
    __shared__ float sProb[H_][TOPK_];

    // phase 0: q rows (scaled) + indices into LDS
    {
        const float* qrow  = qkv + (size_t)bi * (3 * HID_);
        const float* qbrow = qb + (size_t)bi * HID_;
        for (int d = tid; d < HID_; d += 384) {
            sQ[d]  = qrow[d]  * scale;
            sQb[d] = qbrow[d] * scale;
        }
        if (tid < TOPK_) sIdx[tid] = ridx[bi * TOPK_ + tid];
    }
    __syncthreads();

    const int j = sIdx[t];

    // phase 1: random rel/mask gathers — one per thread, all issued at once
    {
        size_t ro = (((size_t)(b * H_ + h)) * L_ + i) * L_ + j;
        sRel[h][t] = rel_pos[ro] + rel2d[ro];
        if (tid < TOPK_) {
            int jj = sIdx[tid];
            sMask[tid] = amask[((size_t)b * L_ + i) * L_ + jj];
            unsigned char f = 1;
            for (int t2 = 0; t2 < tid; ++t2)
                if (sIdx[t2] == jj) { f = 0; break; }
            sFirst[tid] = f;
        }
    }

    // phase 2: both dot products, one thread per (t,h), no cross-lane ops.
    {
        const float* rrow = rbe + ((size_t)bi * TOPK_ + t) * HID_ + h * D_;
        const float* krow = qkv + (size_t)(b * L_ + j) * (3 * HID_) + HID_ + h * D_;
        const float* qbh  = sQb + h * D_;
        const float* qh   = sQ + h * D_;
        float accB0 = 0.f, accB1 = 0.f, accB2 = 0.f, accB3 = 0.f;
        float accK0 = 0.f, accK1 = 0.f, accK2 = 0.f, accK3 = 0.f;
#pragma unroll
        for (int it = 0; it < 16; it += 4) {
            const float4 r0 = *(const float4*)(rrow + (it + 0) * 4);
            const float4 r1 = *(const float4*)(rrow + (it + 1) * 4);
            const float4 r2 = *(const float4*)(rrow + (it + 2) * 4);
            const float4 r3 = *(const float4*)(rrow + (it + 3) * 4);
            const float4 k0 = *(const float4*)(krow + (it + 0) * 4);
            const float4 k1 = *(const float4*)(krow + (it + 1) * 4);
            const float4 k2 = *(const float4*)(krow + (it + 2) * 4);
            const float4 k3 = *(const float4*)(krow + (it + 3) * 4);
            const float4 qb0 = *(const float4*)(qbh + (it + 0) * 4);
            const float4 qb1 = *(const float4*)(qbh + (it + 1) * 4);
            const float4 qb2 = *(const float4*)(qbh + (it + 2) * 4);
            const float4 qb3 = *(const float4*)(qbh + (it + 3) * 4);
            const float4 q0 = *(const float4*)(qh + (it + 0) * 4);
            const float4 q1 = *(const float4*)(qh + (it + 1) * 4);
            const float4 q2 = *(const float4*)(qh + (it + 2) * 4);
            const float4 q3 = *(const float4*)(qh + (it + 3) * 4);
            accB0 = fmaf(r0.x, qb0.x, fmaf(r0.y, qb0.y, fmaf(r0.z, qb0.z, fmaf(r0.w, qb0.w, accB0))));
            accB1 = fmaf(r1.x, qb1.x, fmaf(r1.y, qb1.y, fmaf(r1.z, qb1.z, fmaf(r1.w, qb1.w, accB1))));
            accB2 = fmaf(r2.x, qb2.x, fmaf(r2.y, qb2.y, fmaf(r2.z, qb2.z, fmaf(r2.w, qb2.w, accB2))));
            accB3 = fmaf(r3.x, qb3.x, fmaf(r3.y, qb3.y, fmaf(r3.z, qb3.z, fmaf(r3.w, qb3.w, accB3))));
            accK0 = fmaf(k0.x, q0.x, fmaf(k0.y, q0.y, fmaf(k0.z, q0.z, fmaf(k0.w, q0.w, accK0))));
            accK1 = fmaf(k1.x, q1.x, fmaf(k1.y, q1.y, fmaf(k1.z, q1.z, fmaf(k1.w, q1.w, accK1))));
            accK2 = fmaf(k2.x, q2.x, fmaf(k2.y, q2.y, fmaf(k2.z, q2.z, fmaf(k2.w, q2.w, accK2))));
            accK3 = fmaf(k3.x, q3.x, fmaf(k3.y, q3.y, fmaf(k3.z, q3.z, fmaf(k3.w, q3.w, accK3))));
        }
        sBbox[h][t]  = (accB0 + accB1) + (accB2 + accB3);
        sScore[h][t] = (accK0 + accK1) + (accK2 + accK3) + sRel[h][t];
    }
    __syncthreads();

    // softmax over the <=32 unique columns per head (reduce over t = lane&31)
    {
        float s = -INFINITY;
        if (sFirst[t]) {
            float bb = 0.f;
#pragma unroll
            for (int t2 = 0; t2 < TOPK_; ++t2)
                if (sIdx[t2] == j) bb += sBbox[h][t2];
            s = sScore[h][t] + bb;
            if (sMask[t]) s = NEG_;
        }
        float m = s;
        m = fmaxf(m, __shfl_xor(m, 1));  m = fmaxf(m, __shfl_xor(m, 2));
        m = fmaxf(m, __shfl_xor(m, 4));  m = fmaxf(m, __shfl_xor(m, 8));
        m = fmaxf(m, __shfl_xor(m, 16));
        float e = expf(s - m);
        float sum = e;
        sum += __shfl_xor(sum, 1);  sum += __shfl_xor(sum, 2);
        sum += __shfl_xor(sum, 4);  sum += __shfl_xor(sum, 8);
        sum += __shfl_xor(sum, 16);
        sProb[h][t] = e / sum;
    }
    __syncthreads();

    // ctx: out[h, dd..dd+1] = sum_t p[t] * v[j_t]; 8-wide bounded batches
    {
        const int dd = t * 2;
        const float* vbase = qkv + (size_t)b * L_ * (3 * HID_) + 2 * HID_ + h * D_ + dd;
        float a0 = 0.f, a1 = 0.f;
#pragma unroll
        for (int base = 0; base < TOPK_; base += 8) {
            float2 v[8];
#pragma unroll
            for (int u = 0; u < 8; ++u)
                v[u] = *(const float2*)(vbase + (size_t)sIdx[base + u] * (3 * HID_));
#pragma unroll
            for (int u = 0; u < 8; ++u) {
                float p = sProb[h][base + u];
                a0 = fmaf(p, v[u].x, a0);
                a1 = fmaf(p, v[u].y, a1);
            }
        }
        float2 o; o.x = a0; o.y = a1;
        *(float2*)(out + (size_t)bi * HID_ + h * D_ + dd) = o;
    }
}

// ---------------------------------------------------------------------------
extern "C" void kernel_launch(void* const* d_in, const int* in_sizes, int n_in,
                              void* d_out, int out_size, void* d_ws, size_t ws_size,
                              hipStream_t stream)
{
    const float* hidden  = (const float*)d_in[0];
    const float* rbe     = (const float*)d_in[1];
    const int*   ridx    = (const int*)d_in[2];
    const unsigned char* amask = (const unsigned char*)d_in[3];
    const float* rel_pos = (const float*)d_in[4];
    const float* rel2d   = (const float*)d_in[5];
    const float* w_qkv   = (const float*)d_in[6];
    const float* q_bias  = (const float*)d_in[7];
    const float* v_bias  = (const float*)d_in[8];
    const float* w_rq    = (const float*)d_in[9];
    const float* b_rq    = (const float*)d_in[10];
    float* out = (float*)d_out;

    const int M = B_ * L_;   // 2048
    char* ws = (char*)d_ws;
    float* qkv   = (float*)(ws);                                  // 18.87 MB
    float* qb    = (float*)(ws + 18874368);                       //  6.29 MB
    float* biasq = (float*)(ws + 25165824);                       //  9.2 KB
    __hip_bfloat16* A1  = (__hip_bfloat16*)(ws + 25175040);       //  9.44 MB
    __hip_bfloat16* A2  = (__hip_bfloat16*)(ws + 34612224);       //  9.44 MB
    __hip_bfloat16* Bt1 = (__hip_bfloat16*)(ws + 44049408);       // 10.62 MB
    __hip_bfloat16* Bt2 = (__hip_bfloat16*)(ws + 54666240);       //  3.54 MB

    prep_bias<<<9, 256, 0, stream>>>(q_bias, v_bias, biasq);
    split_a<<<1536, 256, 0, stream>>>(hidden, HID_, A1);
    split_w<<<dim3(2304 / 32, 768 / 32), 256, 0, stream>>>(w_qkv, 3 * HID_, Bt1);
    split_w<<<dim3(768 / 32, 768 / 32), 256, 0, stream>>>(w_rq, HID_, Bt2);

    // qkv = hidden @ w_qkv + [q_bias|0|v_bias]   (128x128: 18x16 = 288 blocks)
    gemm_split<128, 128><<<dim3((3 * HID_) / 128, M / 128), 256, 0, stream>>>(
        A1, Bt1, biasq, qkv, 3 * HID_);

    split_a<<<1536, 256, 0, stream>>>(qkv, 3 * HID_, A2);

    // qb = q @ w_rq + b_rq   (64x64: 12x32 = 384 blocks)
    gemm_split<64, 64><<<dim3(HID_ / 64, M / 64), 256, 0, stream>>>(
        A2, Bt2, b_rq, qb, HID_);

    attn_kernel<<<B_ * L_, 384, 0, stream>>>(qkv, qb, rbe, ridx, amask,
                                             rel_pos, rel2d, out);
}